// Round 7
// baseline (8550.241 us; speedup 1.0000x reference)
//
#include <hip/hip_runtime.h>

// GRU: B=32, S=512, D=1024, H=1024
// out = concat(output[B,S,H], h_last[B,H]) f32
#define B_  32
#define S_  512
#define D_  1024
#define H_  1024
#define G3  3072

typedef __attribute__((ext_vector_type(8))) short  short8;   // 8 x bf16 (4 VGPR)
typedef __attribute__((ext_vector_type(4))) float  floatx4;  // MFMA C/D

__device__ __forceinline__ unsigned short f2bf(float f) {
    unsigned int u = __builtin_bit_cast(unsigned int, f);
    u = (u + 0x7FFFu + ((u >> 16) & 1u)) >> 16;
    return (unsigned short)u;
}
__device__ __forceinline__ float bf2f(unsigned short h) {
    unsigned int u = ((unsigned int)h) << 16;
    return __builtin_bit_cast(float, u);
}
__device__ __forceinline__ float fsigmoid(float x) {
    float e = __builtin_amdgcn_exp2f(-1.4426950408889634f * x);
    return __builtin_amdgcn_rcpf(1.f + e);
}
__device__ __forceinline__ float ftanh(float x) {
    float e = __builtin_amdgcn_exp2f(2.8853900817779268f * x);
    return 1.f - 2.f * __builtin_amdgcn_rcpf(e + 1.f);
}

// ---------------------------------------------------------------------------
// Kernel 0: convert weights f32->bf16 (W_hh hi/lo split), zero h + flags
// ---------------------------------------------------------------------------
__global__ __launch_bounds__(256) void convert_kernel(
    const float* __restrict__ wih, const float* __restrict__ whh,
    unsigned short* __restrict__ wih_h,
    unsigned short* __restrict__ whh_h, unsigned short* __restrict__ whh_l,
    unsigned int* __restrict__ hbuf /* 65536 uints */,
    int* __restrict__ cnt /* 8192 ints: 4 streams x 64 jg x 32-pad */) {
    int tid = blockIdx.x * 256 + threadIdx.x;
    int i4 = tid * 4;
    if (i4 < 3145728) {
        float4 w = *(const float4*)(wih + i4);
        ushort4 o;
        o.x = f2bf(w.x); o.y = f2bf(w.y); o.z = f2bf(w.z); o.w = f2bf(w.w);
        *(ushort4*)(wih_h + i4) = o;

        float4 v = *(const float4*)(whh + i4);
        ushort4 h;
        h.x = f2bf(v.x); h.y = f2bf(v.y); h.z = f2bf(v.z); h.w = f2bf(v.w);
        ushort4 l;
        l.x = f2bf(v.x - bf2f(h.x)); l.y = f2bf(v.y - bf2f(h.y));
        l.z = f2bf(v.z - bf2f(h.z)); l.w = f2bf(v.w - bf2f(h.w));
        *(ushort4*)(whh_h + i4) = h;
        *(ushort4*)(whh_l + i4) = l;
    }
    if (tid < 16384) {  // zero both packed h ping-pong buffers
        uint4 z; z.x = z.y = z.z = z.w = 0;
        *(uint4*)(hbuf + tid * 4) = z;
    }
    if (tid < 2048) {   // zero padded flags (32 KB)
        int4 z4; z4.x = z4.y = z4.z = z4.w = 0;
        *(int4*)(cnt + tid * 4) = z4;
    }
}

// ---------------------------------------------------------------------------
// Kernel 1: gi = feats @ W_ih^T + bias_ih   -> bf16 [B*S][3H]  (unchanged)
// ---------------------------------------------------------------------------
#define BM 128
#define BN 128
#define BK 32
#define LDA 40

__global__ __launch_bounds__(256, 2) void gi_gemm(
    const float* __restrict__ feats,
    const unsigned short* __restrict__ wih_h,
    const float* __restrict__ bias_ih,
    unsigned short* __restrict__ gi) {
    __shared__ unsigned short As[BM * LDA];
    __shared__ unsigned short Bs[BN * LDA];

    int bx = blockIdx.x;
    int nb = bx % (G3 / BN);
    int mb = bx / (G3 / BN);
    int m0 = mb * BM, n0 = nb * BN;
    int tid = threadIdx.x;
    int lane = tid & 63, wave = tid >> 6;
    int quad = lane >> 4, l15 = lane & 15;
    int wm = (wave >> 1) * 64, wn = (wave & 1) * 64;

    floatx4 acc[4][4];
#pragma unroll
    for (int i = 0; i < 4; ++i)
#pragma unroll
        for (int j = 0; j < 4; ++j) acc[i][j] = (floatx4){0.f, 0.f, 0.f, 0.f};

    float bias[4];
#pragma unroll
    for (int j = 0; j < 4; ++j) bias[j] = bias_ih[n0 + wn + j * 16 + l15];

    int srow = tid >> 1, shalf = tid & 1;
    const float* aptr = feats + (size_t)(m0 + srow) * D_ + shalf * 16;
    const unsigned short* bptr = wih_h + (size_t)(n0 + srow) * D_ + shalf * 16;
    unsigned short* as = As + srow * LDA + shalf * 16;
    unsigned short* bs = Bs + srow * LDA + shalf * 16;

    for (int kt = 0; kt < D_ / BK; ++kt) {
        int k0 = kt * BK;
        float4 a0 = *(const float4*)(aptr + k0);
        float4 a1 = *(const float4*)(aptr + k0 + 4);
        float4 a2 = *(const float4*)(aptr + k0 + 8);
        float4 a3 = *(const float4*)(aptr + k0 + 12);
        uint4 bA = *(const uint4*)(bptr + k0);
        uint4 bB = *(const uint4*)(bptr + k0 + 8);

        union { unsigned short u16[16]; uint4 v[2]; } pk;
        pk.u16[0] = f2bf(a0.x);  pk.u16[1] = f2bf(a0.y);
        pk.u16[2] = f2bf(a0.z);  pk.u16[3] = f2bf(a0.w);
        pk.u16[4] = f2bf(a1.x);  pk.u16[5] = f2bf(a1.y);
        pk.u16[6] = f2bf(a1.z);  pk.u16[7] = f2bf(a1.w);
        pk.u16[8] = f2bf(a2.x);  pk.u16[9] = f2bf(a2.y);
        pk.u16[10] = f2bf(a2.z); pk.u16[11] = f2bf(a2.w);
        pk.u16[12] = f2bf(a3.x); pk.u16[13] = f2bf(a3.y);
        pk.u16[14] = f2bf(a3.z); pk.u16[15] = f2bf(a3.w);

        *(uint4*)as = pk.v[0];
        *(uint4*)(as + 8) = pk.v[1];
        *(uint4*)bs = bA;
        *(uint4*)(bs + 8) = bB;
        __syncthreads();

        short8 af[4], bf[4];
#pragma unroll
        for (int i = 0; i < 4; ++i)
            af[i] = *(const short8*)(As + (wm + i * 16 + l15) * LDA + quad * 8);
#pragma unroll
        for (int j = 0; j < 4; ++j)
            bf[j] = *(const short8*)(Bs + (wn + j * 16 + l15) * LDA + quad * 8);
#pragma unroll
        for (int i = 0; i < 4; ++i)
#pragma unroll
            for (int j = 0; j < 4; ++j)
                acc[i][j] = __builtin_amdgcn_mfma_f32_16x16x32_bf16(
                    af[i], bf[j], acc[i][j], 0, 0, 0);
        __syncthreads();
    }

#pragma unroll
    for (int i = 0; i < 4; ++i)
#pragma unroll
        for (int j = 0; j < 4; ++j)
#pragma unroll
            for (int r = 0; r < 4; ++r) {
                int m = m0 + wm + i * 16 + quad * 4 + r;
                int n = n0 + wn + j * 16 + l15;
                gi[(size_t)m * G3 + n] = f2bf(acc[i][j][r] + bias[j]);
            }
}

// ---------------------------------------------------------------------------
// Kernel 2: persistent recurrence — 4-STREAM ROTATION.
// 64 blocks x 512 thr; block jg owns 16 h-cols for 4 independent streams
// (stream s = batch rows 8s..8s+7). Per iteration: 4 phases, one stream-step
// each. Stream s's flag is set 3-4 phases before its poll (phase s-2), its
// h-loads issue at phase s-1, its MFMA consumes at phase s — every L3 round
// trip is hidden under other streams' compute. Protocol primitives verbatim
// from the verified R0/R4 kernel. Flags padded to 128 B.
// ---------------------------------------------------------------------------
__global__ __launch_bounds__(512, 2) void gru_rec(
    const unsigned short* __restrict__ gi,
    const unsigned short* __restrict__ whh_h,
    const unsigned short* __restrict__ whh_l,
    const float* __restrict__ bias_hh,
    unsigned int* __restrict__ hbuf,    // [2][32][1024] packed hi|lo
    int* __restrict__ cnt,              // [4][64][32] padded flags
    float* __restrict__ out) {
    __shared__ floatx4 parts[8][3][64];  // 24 KB
    const float* const pf = (const float*)parts;

    const int tid = threadIdx.x;
    const int lane = tid & 63, ks = tid >> 6;
    const int quad = lane >> 4, l15 = lane & 15;
    const int jg = blockIdx.x;
    const int j = jg * 16 + l15;

    // W_hh fragments (hi+lo): 3 gates x 4 ksteps x 16B = 96 VGPRs
    short8 wfh[3][4], wfl[3][4];
#pragma unroll
    for (int g = 0; g < 3; ++g)
#pragma unroll
        for (int ki = 0; ki < 4; ++ki) {
            size_t off = (size_t)(g * H_ + j) * H_ + ks * 128 + ki * 32 + quad * 8;
            wfh[g][ki] = *(const short8*)(whh_h + off);
            wfl[g][ki] = *(const short8*)(whh_l + off);
        }

    // finish mapping (tid<128): rr 0..7, cc 0..15 -> 1 output per lane
    const int rr = tid >> 4, cc = tid & 15;   // valid when tid < 128
    const int jc = jg * 16 + cc;
    float bR = 0.f, bZ = 0.f, bN = 0.f;
    float hr0 = 0.f, hr1 = 0.f, hr2 = 0.f, hr3 = 0.f;
    if (tid < 128) {
        bR = bias_hh[jc]; bZ = bias_hh[H_ + jc]; bN = bias_hh[2 * H_ + jc];
    }

    const int kbase = ks * 128 + quad * 8;   // uint-col within row of 1024
    const int lidx = ((rr >> 2) * 16 + cc);  // parts addressing (finish)
    const int r4 = rr & 3;

    // register double buffers (static names; lanes l15>=8 stay zero forever)
    short8 ahA[4], alA[4], ahB[4], alB[4];
    const short8 z8 = (short8){0, 0, 0, 0, 0, 0, 0, 0};
#pragma unroll
    for (int ki = 0; ki < 4; ++ki) { ahA[ki] = z8; alA[ki] = z8;
                                     ahB[ki] = z8; alB[ki] = z8; }
    unsigned short gAr = 0, gAz = 0, gAn = 0, gBr = 0, gBz = 0, gBn = 0;

#define LOADH(SN, TL, AH, AL)                                                  \
    if (l15 < 8) {                                                             \
        const unsigned long long* p = (const unsigned long long*)(hbuf +       \
            ((size_t)((TL) & 1) << 15) + (size_t)((SN) * 8 + l15) * H_ + kbase); \
        unsigned long long q[16];                                              \
        _Pragma("unroll")                                                      \
        for (int ki = 0; ki < 4; ++ki)                                         \
            _Pragma("unroll")                                                  \
            for (int c = 0; c < 4; ++c)                                        \
                q[ki * 4 + c] = __hip_atomic_load(p + ki * 16 + c,             \
                    __ATOMIC_RELAXED, __HIP_MEMORY_SCOPE_AGENT);               \
        _Pragma("unroll")                                                      \
        for (int ki = 0; ki < 4; ++ki) {                                       \
            short8 av, lv;                                                     \
            _Pragma("unroll")                                                  \
            for (int c = 0; c < 4; ++c) {                                      \
                unsigned long long qq = q[ki * 4 + c];                         \
                unsigned int u0 = (unsigned int)qq;                            \
                unsigned int u1 = (unsigned int)(qq >> 32);                    \
                av[2 * c]     = (short)(u0 & 0xffffu);                         \
                av[2 * c + 1] = (short)(u1 & 0xffffu);                         \
                lv[2 * c]     = (short)(u0 >> 16);                             \
                lv[2 * c + 1] = (short)(u1 >> 16);                             \
            }                                                                  \
            AH[ki] = av; AL[ki] = lv;                                          \
        }                                                                      \
    }

#define LOADGI(SN, TL, GR, GZ, GN)                                             \
    {                                                                          \
        const size_t gb = ((size_t)((SN) * 8 + rr) * S_ + (TL)) * G3 + jc;     \
        GR = gi[gb]; GZ = gi[gb + H_]; GN = gi[gb + 2 * H_];                   \
    }

#define MFMAB(AH, AL)                                                          \
    {                                                                          \
        floatx4 acc[3];                                                        \
        _Pragma("unroll")                                                      \
        for (int g = 0; g < 3; ++g) acc[g] = (floatx4){0.f, 0.f, 0.f, 0.f};    \
        _Pragma("unroll")                                                      \
        for (int ki = 0; ki < 4; ++ki)                                         \
            _Pragma("unroll")                                                  \
            for (int g = 0; g < 3; ++g) {                                      \
                acc[g] = __builtin_amdgcn_mfma_f32_16x16x32_bf16(AH[ki], wfh[g][ki], acc[g], 0, 0, 0); \
                acc[g] = __builtin_amdgcn_mfma_f32_16x16x32_bf16(AH[ki], wfl[g][ki], acc[g], 0, 0, 0); \
                acc[g] = __builtin_amdgcn_mfma_f32_16x16x32_bf16(AL[ki], wfh[g][ki], acc[g], 0, 0, 0); \
            }                                                                  \
        _Pragma("unroll")                                                      \
        for (int g = 0; g < 3; ++g) parts[ks][g][lane] = acc[g];               \
    }

#define FIN(P, GR, GZ, GN, HR)                                                 \
    {                                                                          \
        float gh0 = 0.f, gh1 = 0.f, gh2 = 0.f;                                 \
        _Pragma("unroll")                                                      \
        for (int w = 0; w < 8; ++w) {                                          \
            gh0 += pf[(((w * 3 + 0) * 64 + lidx) << 2) + r4];                  \
            gh1 += pf[(((w * 3 + 1) * 64 + lidx) << 2) + r4];                  \
            gh2 += pf[(((w * 3 + 2) * 64 + lidx) << 2) + r4];                  \
        }                                                                      \
        const float rg = fsigmoid(bf2f(GR) + gh0 + bR);                        \
        const float zg = fsigmoid(bf2f(GZ) + gh1 + bZ);                        \
        const float ng = ftanh(bf2f(GN) + rg * (gh2 + bN));                    \
        const float hy = ng + zg * (HR - ng);                                  \
        HR = hy;                                                               \
        const unsigned short hh = f2bf(hy);                                    \
        const unsigned int pk = (unsigned int)hh |                             \
                                ((unsigned int)f2bf(hy - bf2f(hh)) << 16);     \
        const int brow = (P) * 8 + rr;                                         \
        __hip_atomic_store(hbuf + ((size_t)((t + 1) & 1) << 15) +              \
                           (size_t)brow * H_ + jc, pk,                         \
                           __ATOMIC_RELAXED, __HIP_MEMORY_SCOPE_AGENT);        \
        asm volatile("s_waitcnt vmcnt(0)" ::: "memory");                       \
        if (tid == 0)                                                          \
            __hip_atomic_store(cnt + ((P) * 64 + jg) * 32, t + 1,              \
                               __ATOMIC_RELAXED, __HIP_MEMORY_SCOPE_AGENT);    \
        __builtin_nontemporal_store(hy, out + ((size_t)brow * S_ + t) * H_ + jc); \
        if (t == S_ - 1)                                                       \
            __builtin_nontemporal_store(hy,                                    \
                out + (size_t)B_ * S_ * H_ + (size_t)brow * H_ + jc);          \
    }

#define POLLF(SS, TP)                                                          \
    {                                                                          \
        const int* fp = cnt + ((SS) * 64 + lane) * 32;                         \
        int v = __hip_atomic_load(fp, __ATOMIC_RELAXED,                        \
                                  __HIP_MEMORY_SCOPE_AGENT);                   \
        while (!__all(v >= (TP))) {                                            \
            __builtin_amdgcn_s_sleep(1);                                       \
            v = __hip_atomic_load(fp, __ATOMIC_RELAXED,                        \
                                  __HIP_MEMORY_SCOPE_AGENT);                   \
        }                                                                      \
    }

#define PHASE(P, AHC, ALC, AHN, ALN, GCr, GCz, GCn, GNr, GNz, GNn, HR)         \
    {                                                                          \
        const int TL = t + ((P) == 3 ? 1 : 0);                                 \
        if (ks >= 2 && TL < S_) { LOADH((((P) + 1) & 3), TL, AHN, ALN); }      \
        MFMAB(AHC, ALC);                                                       \
        __syncthreads();                                                       \
        if (ks < 2) {                                                          \
            FIN(P, GCr, GCz, GCn, HR);                                         \
            if (TL < S_) {                                                     \
                LOADH((((P) + 1) & 3), TL, AHN, ALN);                          \
                LOADGI((((P) + 1) & 3), TL, GNr, GNz, GNn);                    \
            }                                                                  \
        } else if (ks == 2) {                                                  \
            POLLF((((P) + 2) & 3), t + ((P) >= 2 ? 1 : 0));                    \
        }                                                                      \
        __syncthreads();                                                       \
    }

    // prologue: gi for stream 0 step 0 (h(0)=0 already in zeroed regs)
    if (tid < 128) { LOADGI(0, 0, gAr, gAz, gAn); }

    for (int t = 0; t < S_; ++t) {
        PHASE(0, ahA, alA, ahB, alB, gAr, gAz, gAn, gBr, gBz, gBn, hr0);
        PHASE(1, ahB, alB, ahA, alA, gBr, gBz, gBn, gAr, gAz, gAn, hr1);
        PHASE(2, ahA, alA, ahB, alB, gAr, gAz, gAn, gBr, gBz, gBn, hr2);
        PHASE(3, ahB, alB, ahA, alA, gBr, gBz, gBn, gAr, gAz, gAn, hr3);
    }
#undef LOADH
#undef LOADGI
#undef MFMAB
#undef FIN
#undef POLLF
#undef PHASE
}

// ---------------------------------------------------------------------------
extern "C" void kernel_launch(void* const* d_in, const int* in_sizes, int n_in,
                              void* d_out, int out_size, void* d_ws, size_t ws_size,
                              hipStream_t stream) {
    const float* feats = (const float*)d_in[0];
    const float* wih   = (const float*)d_in[1];
    const float* whh   = (const float*)d_in[2];
    const float* bih   = (const float*)d_in[3];
    const float* bhh   = (const float*)d_in[4];
    float* out = (float*)d_out;

    // ws layout (ushorts): wih_h | whh_h | whh_l | gi | hbuf(u32) | cnt
    unsigned short* wih_h = (unsigned short*)d_ws;
    unsigned short* whh_h = wih_h + (size_t)3145728;
    unsigned short* whh_l = whh_h + (size_t)3145728;
    unsigned short* gi    = whh_l + (size_t)3145728;
    unsigned int*   hbuf  = (unsigned int*)(gi + (size_t)16384 * G3);
    int*            cnt   = (int*)(hbuf + 65536);   // 8192 ints (padded flags)

    hipLaunchKernelGGL(convert_kernel, dim3(3072), dim3(256), 0, stream,
                       wih, whh, wih_h, whh_h, whh_l, hbuf, cnt);
    hipLaunchKernelGGL(gi_gemm, dim3(3072), dim3(256), 0, stream,
                       feats, wih_h, bih, gi);

    void* args[] = {(void*)&gi, (void*)&whh_h, (void*)&whh_l,
                    (void*)&bhh, (void*)&hbuf, (void*)&cnt, (void*)&out};
    hipLaunchCooperativeKernel((const void*)gru_rec, dim3(64), dim3(512),
                               args, 0, stream);
}